// Round 19
// baseline (389.437 us; speedup 1.0000x reference)
//
#include <hip/hip_runtime.h>

typedef short short8  __attribute__((ext_vector_type(8)));
typedef float f32x4   __attribute__((ext_vector_type(4)));
typedef float f32x16  __attribute__((ext_vector_type(16)));

#define MFMA32(A,B,C) __builtin_amdgcn_mfma_f32_32x32x16_bf16((A),(B),(C),0,0,0)

__device__ __forceinline__ short bf16bits(float f){
  return (short)__builtin_bit_cast(unsigned short, static_cast<__bf16>(f));
}

// exp(s*0.125 - 8) = exp2(s*0.125*log2e - 8*log2e): one v_fma + v_exp.
// Region mask folded into BIAS: -3e38 -> exp2 == 0 exactly.
#define EXP_SCORE(s, BIAS) __builtin_amdgcn_exp2f(__builtin_fmaf((s), 0.18033688011112042f, (BIAS)))
#define EXP_C2 (-11.541560327111707f)

// ---------------- fused preprocessing ----------------
// blocks [0,220): mask preprocessing  (region_masks -> allowed bits)
// blocks [220,988): K/V repack to bf16 for the 32x32x16 MFMA path.
// All fragment chunks are 1KB = 64 lanes x 16B, lane l at offset l*16
// (conflict-free ds_read_b128 / coalesced global_load by construction).
//   K chunk (kc=key/32, f=d/16): lane = ((d>>3)&1)*32 + (key&31),
//     elem j = d&7  -> holds K[key][d = f*16 + 8*hi + j].
//   V chunk (kc, dblk=d/32, kh): key slot sigma-permuted so the score
//     MFMA's C register file IS the PV B-operand (no P anywhere):
//     C row formula row=(r&3)+8*(r>>2)+4*hi  =>  slot (kh,hi,e) must hold
//     key kappa = 16*kh + (e&3) + 8*(e>>2) + 4*hi. Inverse (given kappa):
//     kh=kappa>>4; rem=kappa&15; hi=(rem>>2)&1; e=(rem&3)+4*(rem>>3).
// (Layouts verified on hardware in rounds 14-18: passed, same absmax.)
__global__ __launch_bounds__(256) void prep_kernel(const float* __restrict__ rm,
                                                   const float* __restrict__ k,
                                                   const float* __restrict__ v,
                                                   const float* __restrict__ rk,
                                                   const float* __restrict__ rv,
                                                   unsigned* __restrict__ allowed,
                                                   unsigned short* __restrict__ Kb,
                                                   unsigned short* __restrict__ VT){
  const int bid = blockIdx.x;
  if (bid < 220){
    int s = bid*256 + threadIdx.x;
    if (s >= 56320) return;
    int t = s / 3520;
    int rem = s - t*3520;
    int i = rem / 80;
    int j = rem - i*80;
    int y = 2*i, x = 2*j;
    bool bin[2];
    #pragma unroll
    for (int r=0;r<2;r++){
      const float* base = rm + (size_t)r*121*88*160;
      float acc;
      if (t == 0){
        const float* p0 = base + (size_t)(0*88 + y)*160 + x;
        acc = 0.25f*(p0[0]+p0[1]+p0[160]+p0[161]);
      } else {
        const float* pa = base + (size_t)((8*t-4)*88 + y)*160 + x;
        const float* pb = base + (size_t)((8*t-3)*88 + y)*160 + x;
        acc = 0.125f*(pa[0]+pa[1]+pa[160]+pa[161] + pb[0]+pb[1]+pb[160]+pb[161]);
      }
      bin[r] = acc > 0.5f;
    }
    unsigned bits = (bin[0]||bin[1]) ? 0u : 1u;
    if (bin[0]) bits |= 2u;
    if (bin[1]) bits |= 4u;
    allowed[s] = bits;
  } else {
    int idx = (bid-220)*256 + threadIdx.x;   // over 3*128*8*64 = 196608
    if (idx >= 3*128*8*64) return;
    int d   = idx & 63;
    int h   = (idx >> 6) & 7;
    int p   = (idx >> 9) & 127;
    int seg = idx >> 16;
    int low = idx & 65535;                   // (p*8+h)*64+d
    float kv_, vv_;
    if (seg == 0){ kv_ = k[low];                          vv_ = v[low]; }
    else         { kv_ = rk[(size_t)(seg-1)*65536 + low]; vv_ = rv[(size_t)(seg-1)*65536 + low]; }
    const int kk = seg*128 + p;              // key index within head, 0..383
    // K fragment placement
    {
      const int f  = d >> 4, hi = (d >> 3) & 1, j = d & 7;
      Kb[(size_t)h*24576 + ((kk>>5)*4 + f)*512
         + (hi*32 + (kk&31))*8 + j] = (unsigned short)bf16bits(kv_);
    }
    // V fragment placement (sigma-permuted key slot)
    {
      const int kap = kk & 31;
      const int kh  = kap >> 4, rem = kap & 15;
      const int hi  = (rem >> 2) & 1;
      const int e   = (rem & 3) + 4*(rem >> 3);
      const int dblk = d >> 5;
      VT[(size_t)h*24576 + ((kk>>5)*4 + dblk*2 + kh)*512
         + (hi*32 + (d&31))*8 + e] = (unsigned short)bf16bits(vv_);
    }
  }
}

// ---------------- fused regional+base attention, PERSISTENT blocks ----------
// ROUND 19: rounds 8-18 (ten structures, 106-128us) proved dur invariant to
// residency, wave count, and load count — the shared property was the
// L2-latency-bound K/V re-read every block generation (55/CU). This kernel
// makes K AND V LDS-RESIDENT for the whole kernel: 256 blocks x 512 thr
// (96KB LDS -> hardware-enforced 1 block/CU, no co-placement possible);
// each block stages its head's K(48K)+V(48K) ONCE via DMA, then loops ~7
// query-chunk iterations (220 chunks x 8 heads / 256 blocks) with ZERO
// global K/V traffic and NO barriers in the loop. Chunk loads become
// ds_read_b128 (~120cy, compiler-scheduled lgkmcnt) instead of L2 (~400+).
// Global traffic collapses to q/out (230MB, the 37us floor) + 24.6MB stage.
// Proven pieces kept: sigma-permuted V (score C regs ARE the PV B-operand,
// no P buffer), identity-lane 1KB chunks (conflict-free), bias-folded exp2,
// 32x32x16 MFMA, compile-time accumulators (r7 rule).
__global__ __launch_bounds__(512, 2)
void attn_kernel(const float* __restrict__ q,
                 const unsigned* __restrict__ allowed,
                 const unsigned short* __restrict__ Kb,
                 const unsigned short* __restrict__ VT,
                 float* __restrict__ out){
  extern __shared__ __align__(16) char smem[];   // 96KB: Ks[48K] | Vs[48K]
  char* Ks = smem;
  char* Vs = smem + 49152;

  const int bid  = blockIdx.x;
  const int h    = bid & 7;          // head
  const int cb   = bid >> 3;         // chunk base 0..31
  const int wave = threadIdx.x >> 6;
  const int lane = threadIdx.x & 63;
  const int qc   = lane & 31;        // query col
  const int hi   = lane >> 5;        // lane half

  // ---- one-time stage: waves 0-3 -> Ks, waves 4-7 -> Vs (12KB each, DMA)
  {
    typedef __attribute__((address_space(1))) const unsigned int gu32_t;
    typedef __attribute__((address_space(3))) unsigned int lu32_t;
    const char* src;
    char* dst;
    if (wave < 4){
      src = (const char*)Kb + (size_t)h*49152 + wave*12288;
      dst = Ks + wave*12288;
    } else {
      src = (const char*)VT + (size_t)h*49152 + (wave-4)*12288;
      dst = Vs + (wave-4)*12288;
    }
    #pragma unroll
    for (int i=0;i<12;i++){
      __builtin_amdgcn_global_load_lds((gu32_t*)(src + i*1024 + lane*16),
                                       (lu32_t*)(dst + i*1024), 16, 0, 0);
    }
  }
  __syncthreads();   // the ONLY barrier: staged K/V visible to all waves

  const char* kfb = Ks + lane*16;    // + (kc*4+f)*1024
  const char* vfb = Vs + lane*16;    // + (kc*4+vfrag)*1024

// one 32-key chunk, all-LDS: 8 ds_read_b128 -> 4 score MFMAs -> exp2(fma,
// mask in bias) -> pf0/pf1 (PV B-frags via sigma) -> 4 PV MFMAs
#define CHUNK(kc, LSUM, BIAS, A0, A1)                                 \
  {                                                                   \
    short8 kf0 = *(const short8*)(kfb + ((kc)*4+0)*1024);             \
    short8 kf1 = *(const short8*)(kfb + ((kc)*4+1)*1024);             \
    short8 kf2 = *(const short8*)(kfb + ((kc)*4+2)*1024);             \
    short8 kf3 = *(const short8*)(kfb + ((kc)*4+3)*1024);             \
    short8 v0  = *(const short8*)(vfb + ((kc)*4+0)*1024);             \
    short8 v1  = *(const short8*)(vfb + ((kc)*4+1)*1024);             \
    short8 v2  = *(const short8*)(vfb + ((kc)*4+2)*1024);             \
    short8 v3  = *(const short8*)(vfb + ((kc)*4+3)*1024);             \
    f32x16 sa = {0,0,0,0,0,0,0,0,0,0,0,0,0,0,0,0};                    \
    sa = MFMA32(kf0, qf0, sa);                                        \
    sa = MFMA32(kf1, qf1, sa);                                        \
    sa = MFMA32(kf2, qf2, sa);                                        \
    sa = MFMA32(kf3, qf3, sa);                                        \
    short8 pf0, pf1;                                                  \
    _Pragma("unroll")                                                 \
    for (int r=0;r<8;r++){                                            \
      float e0 = EXP_SCORE(sa[r],   BIAS); LSUM += e0; pf0[r] = bf16bits(e0); \
      float e1 = EXP_SCORE(sa[8+r], BIAS); LSUM += e1; pf1[r] = bf16bits(e1); \
    }                                                                 \
    A0 = MFMA32(v0, pf0, A0);                                         \
    A0 = MFMA32(v1, pf1, A0);                                         \
    A1 = MFMA32(v2, pf0, A1);                                         \
    A1 = MFMA32(v3, pf1, A1);                                         \
  }

  // ---- persistent loop over this block's query chunks (no barriers)
  #pragma unroll 1
  for (int c = cb; c < 220; c += 32){
    const int s = c*256 + wave*32 + qc;

    const unsigned ab = allowed[s];
    const float* qp = q + ((size_t)s*8 + h)*64 + hi*8;
    f32x4 qa0 = *(const f32x4*)(qp);      f32x4 qb0 = *(const f32x4*)(qp+4);
    f32x4 qa1 = *(const f32x4*)(qp+16);   f32x4 qb1 = *(const f32x4*)(qp+20);
    f32x4 qa2 = *(const f32x4*)(qp+32);   f32x4 qb2 = *(const f32x4*)(qp+36);
    f32x4 qa3 = *(const f32x4*)(qp+48);   f32x4 qb3 = *(const f32x4*)(qp+52);
    short8 qf0, qf1, qf2, qf3;
    #pragma unroll
    for (int j=0;j<4;j++){
      qf0[j]=bf16bits(qa0[j]); qf0[4+j]=bf16bits(qb0[j]);
      qf1[j]=bf16bits(qa1[j]); qf1[4+j]=bf16bits(qb1[j]);
      qf2[j]=bf16bits(qa2[j]); qf2[4+j]=bf16bits(qb2[j]);
      qf3[j]=bf16bits(qa3[j]); qf3[4+j]=bf16bits(qb3[j]);
    }

    const float bias1 = ((ab>>1)&1u) ? EXP_C2 : -3.0e38f;  // region 0
    const float bias2 = ((ab>>2)&1u) ? EXP_C2 : -3.0e38f;  // region 1

    float lb = 0.f, lr = 0.f;
    f32x16 aB0 = {0,0,0,0,0,0,0,0,0,0,0,0,0,0,0,0};
    f32x16 aB1 = {0,0,0,0,0,0,0,0,0,0,0,0,0,0,0,0};
    f32x16 aR0 = {0,0,0,0,0,0,0,0,0,0,0,0,0,0,0,0};
    f32x16 aR1 = {0,0,0,0,0,0,0,0,0,0,0,0,0,0,0,0};

    // base pass (keys 0-127)
    CHUNK(0,  lb, EXP_C2, aB0, aB1);
    CHUNK(1,  lb, EXP_C2, aB0, aB1);
    CHUNK(2,  lb, EXP_C2, aB0, aB1);
    CHUNK(3,  lb, EXP_C2, aB0, aB1);
    // region 0 (keys 128-255)
    CHUNK(4,  lr, bias1,  aR0, aR1);
    CHUNK(5,  lr, bias1,  aR0, aR1);
    CHUNK(6,  lr, bias1,  aR0, aR1);
    CHUNK(7,  lr, bias1,  aR0, aR1);
    // region 1 (keys 256-383)
    CHUNK(8,  lr, bias2,  aR0, aR1);
    CHUNK(9,  lr, bias2,  aR0, aR1);
    CHUNK(10, lr, bias2,  aR0, aR1);
    CHUNK(11, lr, bias2,  aR0, aR1);

    // row sums: lanes l and l^32 hold the two key-halves of one query
    lb += __shfl_xor(lb, 32);
    lr += __shfl_xor(lr, 32);

    const float invb = 0.5f/lb;
    const float lreg = ((ab&1u)? lb : 0.f) + lr;
    const float invr = 0.5f/lreg;
    const float cA   = invb + ((ab&1u)? invr : 0.f);

    // combine and store:
    // reg R=g*4+r of dblk -> d = dblk*32 + 8*g + 4*hi + r (16B f32x4 stores)
    float* ob = out + (size_t)s*512 + h*64 + hi*4;
    #pragma unroll
    for (int g=0; g<4; ++g){
      f32x4 o0, o1;
      #pragma unroll
      for (int r=0;r<4;r++){
        o0[r] = aB0[g*4+r]*cA + aR0[g*4+r]*invr;
        o1[r] = aB1[g*4+r]*cA + aR1[g*4+r]*invr;
      }
      *(f32x4*)(ob + g*8)      = o0;   // dblk 0
      *(f32x4*)(ob + 32 + g*8) = o1;   // dblk 1
    }
  }
}

extern "C" void kernel_launch(void* const* d_in, const int* in_sizes, int n_in,
                              void* d_out, int out_size, void* d_ws, size_t ws_size,
                              hipStream_t stream) {
  const float* q  = (const float*)d_in[0];
  const float* k  = (const float*)d_in[1];
  const float* v  = (const float*)d_in[2];
  const float* rk = (const float*)d_in[3];
  const float* rv = (const float*)d_in[4];
  const float* rm = (const float*)d_in[5];
  float* out = (float*)d_out;

  char* ws = (char*)d_ws;
  unsigned*       allowed = (unsigned*)ws;                           // 56320*4   = 225280 B
  unsigned short* Kb      = (unsigned short*)(ws + 225280);          // 8*3*128*64*2 = 393216 B
  unsigned short* VT      = (unsigned short*)(ws + 225280 + 393216); // 393216 B

  // one-time: allow 96KB dynamic LDS (static __shared__ caps at 64KB)
  static bool attr_done = false;
  if (!attr_done){
    hipFuncSetAttribute(reinterpret_cast<const void*>(attn_kernel),
                        hipFuncAttributeMaxDynamicSharedMemorySize, 98304);
    attr_done = true;
  }

  prep_kernel<<<988, 256, 0, stream>>>(rm, k, v, rk, rv, allowed, Kb, VT);
  attn_kernel<<<256, 512, 98304, stream>>>(q, allowed, Kb, VT, out);
}

// Round 20
// 256.169 us; speedup vs baseline: 1.5202x; 1.5202x over previous
//
#include <hip/hip_runtime.h>

typedef short short8  __attribute__((ext_vector_type(8)));
typedef float f32x4   __attribute__((ext_vector_type(4)));
typedef float f32x16  __attribute__((ext_vector_type(16)));

#define MFMA32(A,B,C) __builtin_amdgcn_mfma_f32_32x32x16_bf16((A),(B),(C),0,0,0)

__device__ __forceinline__ short bf16bits(float f){
  return (short)__builtin_bit_cast(unsigned short, static_cast<__bf16>(f));
}

// exp(s*0.125 - 8) = exp2(s*0.125*log2e - 8*log2e): one v_fma + v_exp.
// Region mask folded into BIAS: -3e38 -> exp2 == 0 exactly.
#define EXP_SCORE(s, BIAS) __builtin_amdgcn_exp2f(__builtin_fmaf((s), 0.18033688011112042f, (BIAS)))
#define EXP_C2 (-11.541560327111707f)

// ---------------- fused preprocessing ----------------
// blocks [0,220): mask preprocessing  (region_masks -> allowed bits)
// blocks [220,988): K/V repack to bf16 for the 32x32x16 MFMA path.
// All fragment chunks are 1KB = 64 lanes x 16B, lane l at offset l*16
// (conflict-free ds_read_b128 / coalesced global_load by construction).
//   K chunk (kc=key/32, f=d/16): lane = ((d>>3)&1)*32 + (key&31),
//     elem j = d&7  -> holds K[key][d = f*16 + 8*hi + j].
//   V chunk (kc, dblk=d/32, kh): key slot sigma-permuted so the score
//     MFMA's C register file IS the PV B-operand (no P anywhere):
//     C row formula row=(r&3)+8*(r>>2)+4*hi  =>  slot (kh,hi,e) must hold
//     key kappa = 16*kh + (e&3) + 8*(e>>2) + 4*hi. Inverse (given kappa):
//     kh=kappa>>4; rem=kappa&15; hi=(rem>>2)&1; e=(rem&3)+4*(rem>>3).
// (Layouts verified on hardware in rounds 14-19: passed, same absmax.)
__global__ __launch_bounds__(256) void prep_kernel(const float* __restrict__ rm,
                                                   const float* __restrict__ k,
                                                   const float* __restrict__ v,
                                                   const float* __restrict__ rk,
                                                   const float* __restrict__ rv,
                                                   unsigned* __restrict__ allowed,
                                                   unsigned short* __restrict__ Kb,
                                                   unsigned short* __restrict__ VT){
  const int bid = blockIdx.x;
  if (bid < 220){
    int s = bid*256 + threadIdx.x;
    if (s >= 56320) return;
    int t = s / 3520;
    int rem = s - t*3520;
    int i = rem / 80;
    int j = rem - i*80;
    int y = 2*i, x = 2*j;
    bool bin[2];
    #pragma unroll
    for (int r=0;r<2;r++){
      const float* base = rm + (size_t)r*121*88*160;
      float acc;
      if (t == 0){
        const float* p0 = base + (size_t)(0*88 + y)*160 + x;
        acc = 0.25f*(p0[0]+p0[1]+p0[160]+p0[161]);
      } else {
        const float* pa = base + (size_t)((8*t-4)*88 + y)*160 + x;
        const float* pb = base + (size_t)((8*t-3)*88 + y)*160 + x;
        acc = 0.125f*(pa[0]+pa[1]+pa[160]+pa[161] + pb[0]+pb[1]+pb[160]+pb[161]);
      }
      bin[r] = acc > 0.5f;
    }
    unsigned bits = (bin[0]||bin[1]) ? 0u : 1u;
    if (bin[0]) bits |= 2u;
    if (bin[1]) bits |= 4u;
    allowed[s] = bits;
  } else {
    int idx = (bid-220)*256 + threadIdx.x;   // over 3*128*8*64 = 196608
    if (idx >= 3*128*8*64) return;
    int d   = idx & 63;
    int h   = (idx >> 6) & 7;
    int p   = (idx >> 9) & 127;
    int seg = idx >> 16;
    int low = idx & 65535;                   // (p*8+h)*64+d
    float kv_, vv_;
    if (seg == 0){ kv_ = k[low];                          vv_ = v[low]; }
    else         { kv_ = rk[(size_t)(seg-1)*65536 + low]; vv_ = rv[(size_t)(seg-1)*65536 + low]; }
    const int kk = seg*128 + p;              // key index within head, 0..383
    // K fragment placement
    {
      const int f  = d >> 4, hi = (d >> 3) & 1, j = d & 7;
      Kb[(size_t)h*24576 + ((kk>>5)*4 + f)*512
         + (hi*32 + (kk&31))*8 + j] = (unsigned short)bf16bits(kv_);
    }
    // V fragment placement (sigma-permuted key slot)
    {
      const int kap = kk & 31;
      const int kh  = kap >> 4, rem = kap & 15;
      const int hi  = (rem >> 2) & 1;
      const int e   = (rem & 3) + 4*(rem >> 3);
      const int dblk = d >> 5;
      VT[(size_t)h*24576 + ((kk>>5)*4 + dblk*2 + kh)*512
         + (hi*32 + (d&31))*8 + e] = (unsigned short)bf16bits(vv_);
    }
  }
}

// ---------------- fused regional+base attention (session-best + setprio) ----
// ROUND 20: revert to the round-15 session-best structure (attn 107.4us,
// e2e 257.9us) — r19's persistent variant spilled (+135MB/iter scratch,
// FETCH 522MB -> genuinely HBM-bound at 246us) and its fix needs a VGPR
// budget the allocator refuses (r17/r18). Additive lever: T5 s_setprio(1)
// around the MFMA clusters — guide-measured +4-7% on attention when
// co-resident waves sit at DIFFERENT phases (m191); our in-loop structure
// is barrier-free and waves are independent, exactly that regime (the
// m190 null was barrier-lockstep GEMM waves).
// Structure: 256 threads (4 waves) per (head, 128-query chunk); 32 queries
// per wave (32x32x16 MFMA). K (48KB) staged once via global_load_lds DMA
// (zero staging VGPRs) -> 3 blocks/CU by LDS; V frags from L2 with
// one-chunk-ahead register prefetch pinned by sched_barrier(0x38F) (r10's
// -11% mechanism); NO P buffer (sigma-permuted V: score C regs ARE the PV
// B-operand); four f32x16 acc sets in regs, all indices compile-time;
// region mask folded into the exp2 bias.
__global__ __launch_bounds__(256)
void attn_kernel(const float* __restrict__ q,
                 const unsigned* __restrict__ allowed,
                 const unsigned short* __restrict__ Kb,
                 const unsigned short* __restrict__ VT,
                 float* __restrict__ out){
  const int h    = blockIdx.y;
  const int wave = threadIdx.x >> 6;
  const int lane = threadIdx.x & 63;
  const int qc   = lane & 31;        // query col
  const int hi   = lane >> 5;        // lane half

  __shared__ __align__(16) char Ks[49152];   // 12 chunks x 4 frags x 1KB

  const int s = blockIdx.x*128 + wave*32 + qc;

  // ---- stage K via DMA (wave-uniform LDS base + lane*16; zero VGPRs)
  {
    typedef __attribute__((address_space(1))) const unsigned int gu32_t;
    typedef __attribute__((address_space(3))) unsigned int lu32_t;
    const char* kg = (const char*)Kb + (size_t)h*49152;
    #pragma unroll
    for (int i=0;i<12;i++){
      const int ub = wave*12288 + i*1024;
      __builtin_amdgcn_global_load_lds((gu32_t*)(kg + ub + lane*16),
                                       (lu32_t*)(Ks + ub), 16, 0, 0);
    }
  }

  // ---- q load -> 4 bf16 frags (lane holds q[s][f*16 + 8*hi + e])
  const unsigned ab = allowed[s];
  const float* qp = q + ((size_t)s*8 + h)*64 + hi*8;
  short8 qf0, qf1, qf2, qf3;
  {
    f32x4 a, b;
    a = *(const f32x4*)(qp);      b = *(const f32x4*)(qp+4);
    #pragma unroll
    for (int j=0;j<4;j++){ qf0[j]=bf16bits(a[j]); qf0[4+j]=bf16bits(b[j]); }
    a = *(const f32x4*)(qp+16);   b = *(const f32x4*)(qp+20);
    #pragma unroll
    for (int j=0;j<4;j++){ qf1[j]=bf16bits(a[j]); qf1[4+j]=bf16bits(b[j]); }
    a = *(const f32x4*)(qp+32);   b = *(const f32x4*)(qp+36);
    #pragma unroll
    for (int j=0;j<4;j++){ qf2[j]=bf16bits(a[j]); qf2[4+j]=bf16bits(b[j]); }
    a = *(const f32x4*)(qp+48);   b = *(const f32x4*)(qp+52);
    #pragma unroll
    for (int j=0;j<4;j++){ qf3[j]=bf16bits(a[j]); qf3[4+j]=bf16bits(b[j]); }
  }

  const char* kfb = Ks + lane*16;                                 // + (kc*4+f)*1024
  const char* vgf = (const char*)VT + (size_t)h*49152 + lane*16;  // global V frags

  // ---- V prefetch buffer (single, compile-time indexed): chunk kc -> 4 frags
  //      v0=(dblk0,kh0) v1=(dblk0,kh1) v2=(dblk1,kh0) v3=(dblk1,kh1)
  short8 v0, v1, v2, v3;
#define VLOAD(kc)                                                     \
  v0 = *(const short8*)(vgf + ((kc)*4+0)*1024);                       \
  v1 = *(const short8*)(vgf + ((kc)*4+1)*1024);                       \
  v2 = *(const short8*)(vgf + ((kc)*4+2)*1024);                       \
  v3 = *(const short8*)(vgf + ((kc)*4+3)*1024);                       \
  __builtin_amdgcn_sched_barrier(0x38F);  /* pin VMEM order only */

// one 32-key chunk: 4 score MFMAs (d-slices) -> exp2(fma, mask in bias)
// -> pf0/pf1 (PV B-frags via sigma) -> 4 PV MFMAs into (A0,A1).
// setprio(1) wraps each MFMA cluster (T5): favors this wave on the CU
// scheduler while co-resident waves are in their load/exp phases.
#define CHUNK(kc, LSUM, BIAS, A0, A1)                                 \
  {                                                                   \
    short8 kf0 = *(const short8*)(kfb + ((kc)*4+0)*1024);             \
    short8 kf1 = *(const short8*)(kfb + ((kc)*4+1)*1024);             \
    short8 kf2 = *(const short8*)(kfb + ((kc)*4+2)*1024);             \
    short8 kf3 = *(const short8*)(kfb + ((kc)*4+3)*1024);             \
    f32x16 sa = {0,0,0,0,0,0,0,0,0,0,0,0,0,0,0,0};                    \
    __builtin_amdgcn_s_setprio(1);                                    \
    sa = MFMA32(kf0, qf0, sa);                                        \
    sa = MFMA32(kf1, qf1, sa);                                        \
    sa = MFMA32(kf2, qf2, sa);                                        \
    sa = MFMA32(kf3, qf3, sa);                                        \
    __builtin_amdgcn_s_setprio(0);                                    \
    short8 pf0, pf1;                                                  \
    _Pragma("unroll")                                                 \
    for (int r=0;r<8;r++){                                            \
      float e0 = EXP_SCORE(sa[r],   BIAS); LSUM += e0; pf0[r] = bf16bits(e0); \
      float e1 = EXP_SCORE(sa[8+r], BIAS); LSUM += e1; pf1[r] = bf16bits(e1); \
    }                                                                 \
    __builtin_amdgcn_s_setprio(1);                                    \
    A0 = MFMA32(v0, pf0, A0);                                         \
    A0 = MFMA32(v1, pf1, A0);                                         \
    A1 = MFMA32(v2, pf0, A1);                                         \
    A1 = MFMA32(v3, pf1, A1);                                         \
    __builtin_amdgcn_s_setprio(0);                                    \
  }

  VLOAD(0);          // drained by the barrier alongside the K DMA

  __syncthreads();   // staged K visible to all waves

  const float bias1 = ((ab>>1)&1u) ? EXP_C2 : -3.0e38f;  // region 0 (chunks 4-7)
  const float bias2 = ((ab>>2)&1u) ? EXP_C2 : -3.0e38f;  // region 1 (chunks 8-11)

  float lb = 0.f, lr = 0.f;
  f32x16 aB0 = {0,0,0,0,0,0,0,0,0,0,0,0,0,0,0,0};
  f32x16 aB1 = {0,0,0,0,0,0,0,0,0,0,0,0,0,0,0,0};
  f32x16 aR0 = {0,0,0,0,0,0,0,0,0,0,0,0,0,0,0,0};
  f32x16 aR1 = {0,0,0,0,0,0,0,0,0,0,0,0,0,0,0,0};

  // ---- base pass (keys 0-127) -> aB*
  CHUNK(0, lb, EXP_C2, aB0, aB1); VLOAD(1);
  CHUNK(1, lb, EXP_C2, aB0, aB1); VLOAD(2);
  CHUNK(2, lb, EXP_C2, aB0, aB1); VLOAD(3);
  CHUNK(3, lb, EXP_C2, aB0, aB1); VLOAD(4);

  // ---- regional pass (keys 128-383) -> aR*
  CHUNK(4,  lr, bias1, aR0, aR1); VLOAD(5);
  CHUNK(5,  lr, bias1, aR0, aR1); VLOAD(6);
  CHUNK(6,  lr, bias1, aR0, aR1); VLOAD(7);
  CHUNK(7,  lr, bias1, aR0, aR1); VLOAD(8);
  CHUNK(8,  lr, bias2, aR0, aR1); VLOAD(9);
  CHUNK(9,  lr, bias2, aR0, aR1); VLOAD(10);
  CHUNK(10, lr, bias2, aR0, aR1); VLOAD(11);
  CHUNK(11, lr, bias2, aR0, aR1);

  // ---- row sums: lanes l and l^32 hold the two key-halves of one query
  lb += __shfl_xor(lb, 32);
  lr += __shfl_xor(lr, 32);

  const float invb = 0.5f/lb;
  const float lreg = ((ab&1u)? lb : 0.f) + lr;
  const float invr = 0.5f/lreg;
  const float cA   = invb + ((ab&1u)? invr : 0.f);

  // ---- combine and store:
  // reg R=g*4+r of dblk -> d = dblk*32 + 8*g + 4*hi + r  (16B f32x4 stores)
  float* ob = out + (size_t)s*512 + h*64 + hi*4;
  #pragma unroll
  for (int g=0; g<4; ++g){
    f32x4 o0, o1;
    #pragma unroll
    for (int r=0;r<4;r++){
      o0[r] = aB0[g*4+r]*cA + aR0[g*4+r]*invr;
      o1[r] = aB1[g*4+r]*cA + aR1[g*4+r]*invr;
    }
    *(f32x4*)(ob + g*8)      = o0;   // dblk 0
    *(f32x4*)(ob + 32 + g*8) = o1;   // dblk 1
  }
}

extern "C" void kernel_launch(void* const* d_in, const int* in_sizes, int n_in,
                              void* d_out, int out_size, void* d_ws, size_t ws_size,
                              hipStream_t stream) {
  const float* q  = (const float*)d_in[0];
  const float* k  = (const float*)d_in[1];
  const float* v  = (const float*)d_in[2];
  const float* rk = (const float*)d_in[3];
  const float* rv = (const float*)d_in[4];
  const float* rm = (const float*)d_in[5];
  float* out = (float*)d_out;

  char* ws = (char*)d_ws;
  unsigned*       allowed = (unsigned*)ws;                           // 56320*4   = 225280 B
  unsigned short* Kb      = (unsigned short*)(ws + 225280);          // 8*3*128*64*2 = 393216 B
  unsigned short* VT      = (unsigned short*)(ws + 225280 + 393216); // 393216 B

  prep_kernel<<<988, 256, 0, stream>>>(rm, k, v, rk, rv, allowed, Kb, VT);
  dim3 grid(440, 8);
  attn_kernel<<<grid, 256, 0, stream>>>(q, allowed, Kb, VT, out);
}